// Round 2
// 622.530 us; speedup vs baseline: 1.0437x; 1.0437x over previous
//
#include <hip/hip_runtime.h>

// Cost-volume construction, out (B=2, 2C=64, D=64, H=80, W=240) fp32 = 629 MB.
//   out[b][c   ][d][h][w] = x[b][c][h][w]   * (w>=d)
//   out[b][32+c][d][h][w] = y[b][c][h][w-d] * (w>=d)
//
// One block per (b,c,h) row; 256 threads = 4 waves. Stage x-row + zero-padded
// y-row in LDS. Wave wv owns d = wv, wv+4, ..., 60+wv  =>  d is WAVE-UNIFORM:
//  - left half:  the x float4 is loop-invariant (1 ds_read_b128 per thread,
//    was 15); masking = 4 compares vs uniform d.
//  - right half: shift r = (64+4*lane-d)&3 = (-wv)&3 is constant per wave ->
//    template-specialized splice of two ALIGNED b128 quads (dense, conflict-
//    free) with a sliding window: qa drops by 1 per d-step, so 17 b128 reads
//    feed 16 stores (was 60 8-way-conflicted ds_read_b32).
// All output stores are nontemporal (write-once, never re-read; don't thrash
// the 4MB/XCD L2 + 256MB L3 with 629 MB of dirty lines). Stores go through a
// clang ext_vector_type(4) alias: __builtin_nontemporal_store rejects the
// HIP_vector_type class float4*.

#define W4    60u       // float4 per row (W=240)
#define CH4   307200u   // D*H*W4 = 64*80*60  float4 per output channel
#define D4    4800u     // H*W4   = 80*60     float4 per d-slice

typedef float f32x4 __attribute__((ext_vector_type(4)));

__device__ __forceinline__ void nt_store4(float4 v, float4* p) {
    f32x4 t; t.x = v.x; t.y = v.y; t.z = v.z; t.w = v.w;
    __builtin_nontemporal_store(t, reinterpret_cast<f32x4*>(p));
}

template <int R>
__device__ __forceinline__ float4 splice(float4 a, float4 b) {
    if constexpr (R == 0)      return a;
    else if constexpr (R == 1) return make_float4(a.y, a.z, a.w, b.x);
    else if constexpr (R == 2) return make_float4(a.z, a.w, b.x, b.y);
    else                       return make_float4(a.w, b.x, b.y, b.z);
}

template <int R>
__device__ __forceinline__ void right_half(const float4* __restrict__ yq,
                                           float4* __restrict__ out4,
                                           unsigned lane, unsigned wv,
                                           unsigned baseR) {
    // k-th iter handles d = wv + 4k; window start p = 64 + 4*lane - d,
    // p & 3 == R (wave-constant), qa = p >> 2 decrements by 1 each iter.
    unsigned qa  = (64u + 4u * lane - wv - (unsigned)R) >> 2;
    unsigned off = baseR + wv * D4 + lane;
    float4 q1 = yq[qa + 1u];   // only consumed for R>0 (pad makes it safe)
    float4 q0 = yq[qa];
    #pragma unroll
    for (unsigned k = 0; k < 16u; ++k) {
        nt_store4(splice<R>(q0, q1), &out4[off]);
        off += 4u * D4;
        q1 = q0;
        if (k + 1u < 16u) q0 = yq[--qa];
    }
}

__global__ __launch_bounds__(256) void costvol_kernel(const float* __restrict__ x,
                                                      const float* __restrict__ y,
                                                      float* __restrict__ out) {
    __shared__ __align__(16) float xs[240];
    __shared__ __align__(16) float ysbuf[308];   // [0,64)=0 pad, [64,304)=y row, [304,308) read-only slack

    const unsigned t   = threadIdx.x;
    const unsigned blk = blockIdx.x;             // (b*32 + c)*80 + h
    const unsigned h   = blk % 80u;
    const unsigned bc  = blk / 80u;              // b*32 + c
    const unsigned c   = bc % 32u;
    const unsigned b   = bc / 32u;

    const float4* xrow = (const float4*)(x + (size_t)blk * 240u);
    const float4* yrow = (const float4*)(y + (size_t)blk * 240u);
    float4* xsq = (float4*)xs;
    float4* ysq = (float4*)ysbuf;

    // Cooperative staging: 16 zero quads + 60 y quads (+1 zero slack), 60 x quads.
    if (t < 16u)                 ysq[t]        = make_float4(0.f, 0.f, 0.f, 0.f);
    else if (t < 76u)            ysq[t]        = yrow[t - 16u];
    else if (t == 76u)           ysq[76]       = make_float4(0.f, 0.f, 0.f, 0.f);
    if (t >= 128u && t < 188u)   xsq[t - 128u] = xrow[t - 128u];
    __syncthreads();

    const unsigned lane = t & 63u;
    const unsigned wv   = t >> 6;                // wave id, 0..3
    if (lane >= 60u) return;                     // 60 quads per row

    float4* out4 = (float4*)out;
    const unsigned baseL = (b * 64u + c) * CH4 + h * W4;
    const unsigned baseR = baseL + 32u * CH4;

    // ---- Left half: x masked by (w >= d). x-quad is d-invariant. ----
    {
        const float4 xv = xsq[lane];             // one dense b128, conflict-free
        const int w0 = 4 * (int)lane;
        unsigned off = baseL + wv * D4 + lane;
        #pragma unroll
        for (unsigned k = 0; k < 16u; ++k) {
            const int d = (int)(wv + 4u * k);    // wave-uniform
            float4 v = xv;
            if (w0 + 0 < d) v.x = 0.f;
            if (w0 + 1 < d) v.y = 0.f;
            if (w0 + 2 < d) v.z = 0.f;
            if (w0 + 3 < d) v.w = 0.f;
            nt_store4(v, &out4[off]);
            off += 4u * D4;
        }
    }

    // ---- Right half: shifted y; shift mod 4 is constant per wave. ----
    switch (wv) {
        case 0:  right_half<0>(ysq, out4, lane, wv, baseR); break;
        case 1:  right_half<3>(ysq, out4, lane, wv, baseR); break;
        case 2:  right_half<2>(ysq, out4, lane, wv, baseR); break;
        default: right_half<1>(ysq, out4, lane, wv, baseR); break;
    }
}

extern "C" void kernel_launch(void* const* d_in, const int* in_sizes, int n_in,
                              void* d_out, int out_size, void* d_ws, size_t ws_size,
                              hipStream_t stream) {
    const float* x = (const float*)d_in[0];
    const float* y = (const float*)d_in[1];
    float* out     = (float*)d_out;

    dim3 grid(2u * 32u * 80u), block(256);       // one block per (b,c,h) row
    hipLaunchKernelGGL(costvol_kernel, grid, block, 0, stream, x, y, out);
}